// Round 14
// baseline (241.001 us; speedup 1.0000x reference)
//
#include <hip/hip_runtime.h>
#include <hip/hip_bf16.h>
#include <math.h>

// Problem constants
#define NN 50000
#define EE 800000
#define NB_SCAN 49   // ceil(50000/1024)
#define NBLK_CS 64   // counting-sort blocks
#define EPB (EE / NBLK_CS)  // 12500 edges per block

typedef __attribute__((ext_vector_type(8))) short bf16x8;
typedef __attribute__((ext_vector_type(4))) float f32x4;
typedef __attribute__((ext_vector_type(8))) unsigned short ushortx8;

// ---------------- workspace layout (bytes); regions phase-disjoint ----------
#define OFF_XBF   ((size_t)0)           // N*128 bf16 = 12.8M (prep..gemm1)
#define OFF_XL2B  ((size_t)0)           // N*40 bf16 = 4M (gemm2..end)
#define OFF_XR2   ((size_t)4000000)     // N*40 f32 = 8M (gemm2..end)
#define OFF_XL1B  ((size_t)12800000)    // N*128 bf16 = 12.8M (gemm1..head1)
#define OFF_H1B   ((size_t)12800000)    // N*128 bf16 (ln1..gemm2; XL1B dead)
#define OFF_XR1   ((size_t)25600000)    // N*128 f32 = 25.6M (gemm1..head1)
// [51.2M,76.8M): CSR-build scratch (HB,BOFF; dead before head1) then H1PRE
#define OFF_HB    ((size_t)51200000)    // 64*N u8 = 3.2M (cs_hist..cs_boff)
#define OFF_BOFF  ((size_t)54400000)    // 64*N int = 12.8M (cs_boff..cs_scatter)
#define OFF_H1PRE ((size_t)51200000)    // N*128 f32 = 25.6M (head1..ln1)
#define OFF_S1    ((size_t)76800000)    // N*4 f32 = 800,000
#define OFF_BP1   ((size_t)77600000)    // 32768 bf16
#define OFF_BP2   ((size_t)77665536)    // 10240 bf16
#define OFF_BB1   ((size_t)77686016)    // 256 f32
#define OFF_BB2   ((size_t)77687040)    // 80 f32 (pad 512)
#define OFF_DEG   ((size_t)77687552)    // N int
#define OFF_OFFS  ((size_t)77887552)    // (N+1) int
#define OFF_BSUM  ((size_t)78087808)    // 64 int (pad 256)
#define OFF_CSR   ((size_t)78088064)    // E int = 3.2M (src per CSR pos)

// ---------------- helpers (proven) ----------------
__device__ __forceinline__ unsigned short f2bf(float f) {
    union { float f; unsigned u; } v;
    v.f = f;
    unsigned r = v.u + 0x7fffu + ((v.u >> 16) & 1u);
    return (unsigned short)(r >> 16);
}
__device__ __forceinline__ float bfl(unsigned u) {
    union { unsigned u; float f; } v;
    v.u = u << 16;
    return v.f;
}
__device__ __forceinline__ float bfh(unsigned u) {
    union { unsigned u; float f; } v;
    v.u = u & 0xffff0000u;
    return v.f;
}
__device__ __forceinline__ float lrelu02(float h) { return fmaxf(h, 0.2f * h); }

// ---------------- prep: cvt x->bf16 + pack weights (pure streaming) ---------
__global__ void prep_kernel(
    const float* __restrict__ x, unsigned short* __restrict__ XBF,
    const float* __restrict__ Wl1, const float* __restrict__ bl1,
    const float* __restrict__ Wr1, const float* __restrict__ br1,
    const float* __restrict__ Wl2, const float* __restrict__ bl2,
    const float* __restrict__ Wr2, const float* __restrict__ br2,
    unsigned short* __restrict__ BP1, float* __restrict__ BB1,
    unsigned short* __restrict__ BP2, float* __restrict__ BB2) {
    int i = blockIdx.x * blockDim.x + threadIdx.x;
    if (i < NN * 128 / 8) {
        const float4* p = (const float4*)x + (size_t)i * 2;
        float4 v0 = p[0], v1 = p[1];
        ushortx8 o;
        o[0] = f2bf(v0.x); o[1] = f2bf(v0.y); o[2] = f2bf(v0.z); o[3] = f2bf(v0.w);
        o[4] = f2bf(v1.x); o[5] = f2bf(v1.y); o[6] = f2bf(v1.z); o[7] = f2bf(v1.w);
        *((ushortx8*)XBF + i) = o;
    }
    if (i < 32768) {  // layer 1 B-pack: NT=16
        int j = i & 7, l = (i >> 3) & 63, nt = (i >> 9) & 15, kt = i >> 13;
        int k = kt * 32 + ((l >> 4) << 3) + j;
        int n = nt * 16 + (l & 15);
        float v = (n < 128) ? Wl1[k * 128 + n] : Wr1[k * 128 + (n - 128)];
        BP1[i] = f2bf(v);
    }
    if (i < 10240) {  // layer 2 B-pack: NT=5
        int j = i & 7, l = (i >> 3) & 63;
        int rest = i >> 9;
        int nt = rest % 5, kt = rest / 5;
        int k = kt * 32 + ((l >> 4) << 3) + j;
        int n = nt * 16 + (l & 15);
        float v = (n < 40) ? Wl2[k * 40 + n] : Wr2[k * 40 + (n - 40)];
        BP2[i] = f2bf(v);
    }
    if (i < 256) BB1[i] = (i < 128) ? bl1[i] : br1[i - 128];
    if (i < 80) BB2[i] = (i < 40) ? bl2[i] : br2[i - 40];
}

// ---------------- counting-sort CSR build (no global atomics) ---------------
// H1: per-block LDS histogram (packed u8 over all 50000 targets) -> HB[b][t]
__global__ __launch_bounds__(1024) void cs_hist_kernel(
    const int* __restrict__ tgts, unsigned char* __restrict__ HB) {
    __shared__ unsigned int cnt[NN / 4];  // 12500 u32 = 50000 packed u8
    int b = blockIdx.x;
    for (int i = threadIdx.x; i < NN / 4; i += 1024) cnt[i] = 0;
    __syncthreads();
    int e0 = b * EPB;
    for (int i = threadIdx.x; i < EPB; i += 1024) {
        int t = tgts[e0 + i];
        atomicAdd(&cnt[t >> 2], 1u << ((t & 3) * 8));
    }
    __syncthreads();
    unsigned int* out = (unsigned int*)(HB + (size_t)b * NN);
    for (int i = threadIdx.x; i < NN / 4; i += 1024) out[i] = cnt[i];
}

// H2: per-target prefix over block counts -> BOFF[b][t]; DEG[t] = total
__global__ void cs_boff_kernel(const unsigned char* __restrict__ HB,
                               int* __restrict__ BOFF, int* __restrict__ DEG) {
    int t = blockIdx.x * 256 + threadIdx.x;
    if (t >= NN) return;
    int run = 0;
#pragma unroll
    for (int b = 0; b < NBLK_CS; ++b) {
        BOFF[(size_t)b * NN + t] = run;
        run += HB[(size_t)b * NN + t];
    }
    DEG[t] = run;
}

// H3: replay LDS histogram for local rank; pos = OFFS[t] + BOFF[b][t] + r
__global__ __launch_bounds__(1024) void cs_scatter_kernel(
    const int* __restrict__ srcs, const int* __restrict__ tgts,
    const int* __restrict__ off, const int* __restrict__ boff,
    int* __restrict__ csr) {
    __shared__ unsigned int cnt[NN / 4];
    int b = blockIdx.x;
    for (int i = threadIdx.x; i < NN / 4; i += 1024) cnt[i] = 0;
    __syncthreads();
    int e0 = b * EPB;
    const int* bo = boff + (size_t)b * NN;
    for (int i = threadIdx.x; i < EPB; i += 1024) {
        int t = tgts[e0 + i];
        int sh = (t & 3) * 8;
        unsigned old = atomicAdd(&cnt[t >> 2], 1u << sh);
        int r = (old >> sh) & 0xFF;
        csr[off[t] + bo[t] + r] = srcs[e0 + i];
    }
}

// ---------------- parallel scan (proven) ----------------
__global__ __launch_bounds__(1024) void scan_bsum_kernel(
    const int* __restrict__ deg, int* __restrict__ bsum, int n) {
    __shared__ int ws[16];
    int lane = threadIdx.x & 63, w = threadIdx.x >> 6;
    int i = blockIdx.x * 1024 + threadIdx.x;
    int v = (i < n) ? deg[i] : 0;
#pragma unroll
    for (int d = 32; d >= 1; d >>= 1) v += __shfl_xor(v, d, 64);
    if (lane == 0) ws[w] = v;
    __syncthreads();
    if (threadIdx.x < 16) {
        int xv = ws[threadIdx.x];
#pragma unroll
        for (int d = 8; d >= 1; d >>= 1) xv += __shfl_xor(xv, d, 16);
        if (threadIdx.x == 0) bsum[blockIdx.x] = xv;
    }
}

__global__ __launch_bounds__(1024) void scan_final_kernel(
    const int* __restrict__ deg, const int* __restrict__ bsum,
    int* __restrict__ off, int n) {
    __shared__ int wsum[16];
    __shared__ int carrySh;
    int lane = threadIdx.x & 63, w = threadIdx.x >> 6;
    if (threadIdx.x < 64) {
        int v = ((int)threadIdx.x < (int)blockIdx.x) ? bsum[threadIdx.x] : 0;
#pragma unroll
        for (int d = 32; d >= 1; d >>= 1) v += __shfl_xor(v, d, 64);
        if (threadIdx.x == 0) carrySh = v;
    }
    int i = blockIdx.x * 1024 + threadIdx.x;
    int v = (i < n) ? deg[i] : 0;
    int incl = v;
#pragma unroll
    for (int d = 1; d < 64; d <<= 1) {
        int t = __shfl_up(incl, d, 64);
        if (lane >= d) incl += t;
    }
    if (lane == 63) wsum[w] = incl;
    __syncthreads();
    if (threadIdx.x < 16) {
        int xv = wsum[threadIdx.x];
#pragma unroll
        for (int d = 1; d < 16; d <<= 1) {
            int t = __shfl_up(xv, d, 16);
            if ((int)threadIdx.x >= d) xv += t;
        }
        wsum[threadIdx.x] = xv;
    }
    __syncthreads();
    int add = (w > 0) ? wsum[w - 1] : 0;
    int carry = carrySh;
    if (i < n) off[i + 1] = carry + incl + add;
    if (i == 0) off[0] = 0;
}

// ---------------- bf16 MFMA GEMM: split bf16/f32 outputs ---------------------
__global__ __launch_bounds__(256) void gemm_mfma_kernel(
    const unsigned short* __restrict__ Abf, const unsigned short* __restrict__ BP,
    const float* __restrict__ bias, unsigned short* __restrict__ Cbf,
    float* __restrict__ Cf, int M, int NT, int NSPLIT) {
    int wave = (blockIdx.x * blockDim.x + threadIdx.x) >> 6;
    int lane = threadIdx.x & 63;
    int r0 = wave * 16;
    if (r0 >= M) return;
    int koff = (lane >> 4) << 3;
    const unsigned short* ap = &Abf[(size_t)(r0 + (lane & 15)) * 128 + koff];
    bf16x8 a0 = *(const bf16x8*)(ap);
    bf16x8 a1 = *(const bf16x8*)(ap + 32);
    bf16x8 a2 = *(const bf16x8*)(ap + 64);
    bf16x8 a3 = *(const bf16x8*)(ap + 96);
    int NR = (NT << 4) - NSPLIT;
    int col = lane & 15;
    int rb = r0 + ((lane >> 4) << 2);
    size_t ktStride = (size_t)NT * 512;
    for (int nt = 0; nt < NT; ++nt) {
        const unsigned short* bp = &BP[((size_t)nt * 64 + lane) * 8];
        f32x4 acc = {0.f, 0.f, 0.f, 0.f};
        acc = __builtin_amdgcn_mfma_f32_16x16x32_bf16(a0, *(const bf16x8*)(bp), acc, 0, 0, 0);
        acc = __builtin_amdgcn_mfma_f32_16x16x32_bf16(a1, *(const bf16x8*)(bp + ktStride), acc, 0, 0, 0);
        acc = __builtin_amdgcn_mfma_f32_16x16x32_bf16(a2, *(const bf16x8*)(bp + 2 * ktStride), acc, 0, 0, 0);
        acc = __builtin_amdgcn_mfma_f32_16x16x32_bf16(a3, *(const bf16x8*)(bp + 3 * ktStride), acc, 0, 0, 0);
        int c = (nt << 4) + col;
        float bb = bias[c];
        if (c < NSPLIT) {
#pragma unroll
            for (int j = 0; j < 4; ++j) Cbf[(size_t)(rb + j) * NSPLIT + c] = f2bf(acc[j] + bb);
        } else {
#pragma unroll
            for (int j = 0; j < 4; ++j) Cf[(size_t)(rb + j) * NR + (c - NSPLIT)] = acc[j] + bb;
        }
    }
}

// ---------------- layer-1 per-head fused score+agg kernel --------------------
__global__ __launch_bounds__(256) void gat_head1_kernel(
    const unsigned short* __restrict__ XL1B, const float* __restrict__ XR1,
    const int* __restrict__ off, const int* __restrict__ csr,
    const float* __restrict__ att, float* __restrict__ H1pre,
    float* __restrict__ S1, int cb) {
    int wid = threadIdx.x >> 6;
    int lane = threadIdx.x & 63;
    int node = blockIdx.x * 4 + wid;
    if (node >= NN) return;
    int grp = lane >> 4;
    int sub = lane & 15;
    int coff = cb * 32 + sub * 2;
    float2 xr = *(const float2*)&XR1[(size_t)node * 128 + coff];
    float2 at = *(const float2*)&att[coff];
    const unsigned short* base = XL1B + coff;
    float a0 = 0.f, a1 = 0.f, sl = 0.f;
    int jb = off[node], je = off[node + 1];
    int deg = je - jb;

    auto proc = [&](int srcv, int eo) {
        unsigned u = *(const unsigned*)(base + (size_t)srcv * 128);
        float x0 = bfl(u), x1 = bfh(u);
        float t = lrelu02(x0 + xr.x) * at.x;
        t = fmaf(lrelu02(x1 + xr.y), at.y, t);
        t += __shfl_xor(t, 1, 64);
        t += __shfl_xor(t, 2, 64);
        t += __shfl_xor(t, 4, 64);
        t += __shfl_xor(t, 8, 64);       // head score over 16 subs
        t = (eo < deg) ? t : -1e30f;
        float p = __expf(t);
        a0 = fmaf(p, x0, a0);
        a1 = fmaf(p, x1, a1);
        sl += p;
    };

    for (int ch = 0; ch < deg; ch += 16) {
        int sidx = csr[min(jb + ch + sub, je - 1)];
        int s0 = __shfl(sidx, grp, 16);
        int s1 = __shfl(sidx, 4 + grp, 16);
        int s2 = __shfl(sidx, 8 + grp, 16);
        int s3 = __shfl(sidx, 12 + grp, 16);
        proc(s0, ch + grp);
        proc(s1, ch + 4 + grp);
        proc(s2, ch + 8 + grp);
        proc(s3, ch + 12 + grp);
    }
#pragma unroll
    for (int d = 16; d <= 32; d <<= 1) {
        a0 += __shfl_xor(a0, d, 64);
        a1 += __shfl_xor(a1, d, 64);
        sl += __shfl_xor(sl, d, 64);
    }
    if (grp == 0) {
        float2 v;
        v.x = a0;
        v.y = a1;
        *(float2*)&H1pre[(size_t)node * 128 + coff] = v;
        if (sub == 0) S1[node * 4 + cb] = sl;
    }
}

// ---------------- layer-1 divide + bias + LN + ELU -> H1 bf16 ---------------
__global__ __launch_bounds__(256) void ln1_kernel(
    const float* __restrict__ H1pre, const float* __restrict__ S1,
    const float* __restrict__ b1, const float* __restrict__ g1,
    const float* __restrict__ be1, unsigned short* __restrict__ H1B) {
    int wid = threadIdx.x >> 6;
    int lane = threadIdx.x & 63;
    int node = blockIdx.x * 4 + wid;
    if (node >= NN) return;
    int c = lane * 2;
    float2 v = *(const float2*)&H1pre[(size_t)node * 128 + c];
    float sl = S1[node * 4 + (lane >> 4)];
    float inv = 1.f / (sl + 1e-16f);
    float o0 = v.x * inv + b1[c];
    float o1 = v.y * inv + b1[c + 1];
    float sum = o0 + o1, sq = o0 * o0 + o1 * o1;
#pragma unroll
    for (int d = 32; d >= 1; d >>= 1) {
        sum += __shfl_xor(sum, d, 64);
        sq += __shfl_xor(sq, d, 64);
    }
    float mu = sum * (1.f / 128.f);
    float var = sq * (1.f / 128.f) - mu * mu;
    float rs = rsqrtf(var + 1e-5f);
    float y0 = (o0 - mu) * rs * g1[c] + be1[c];
    float y1 = (o1 - mu) * rs * g1[c + 1] + be1[c + 1];
    y0 = y0 > 0.f ? y0 : expm1f(y0);
    y1 = y1 > 0.f ? y1 : expm1f(y1);
    unsigned o = (unsigned)f2bf(y0) | ((unsigned)f2bf(y1) << 16);
    ((unsigned*)H1B)[(size_t)node * 64 + lane] = o;
}

// ---------------- layer-2 fused score+agg (single head, 40ch) ---------------
__global__ __launch_bounds__(256) void gat_edge2_kernel(
    const unsigned short* __restrict__ XL2B, const float* __restrict__ XR2,
    const int* __restrict__ off, const int* __restrict__ csr,
    const float* __restrict__ att2, const float* __restrict__ b2,
    float* __restrict__ Y) {
    int wid = threadIdx.x >> 6;
    int lane = threadIdx.x & 63;
    int node = blockIdx.x * 4 + wid;
    if (node >= NN) return;
    int grp = lane >> 4;
    int sub = lane & 15;
    bool chact = sub < 10;
    int cld = chact ? sub * 4 : 0;
    float4 xr = make_float4(0.f, 0.f, 0.f, 0.f);
    float4 at = make_float4(0.f, 0.f, 0.f, 0.f);
    if (chact) {
        xr = *(const float4*)&XR2[(size_t)node * 40 + cld];
        at = *(const float4*)&att2[cld];
    }
    float a0 = 0.f, a1 = 0.f, a2 = 0.f, a3 = 0.f, sl = 0.f;
    int jb = off[node], je = off[node + 1];
    int deg = je - jb;

    auto proc = [&](int srcv, int eo) {
        uint2 u = *(const uint2*)(XL2B + (size_t)srcv * 40 + cld);
        float x0 = bfl(u.x), x1 = bfh(u.x), x2 = bfl(u.y), x3 = bfh(u.y);
        float t = lrelu02(x0 + xr.x) * at.x;
        t = fmaf(lrelu02(x1 + xr.y), at.y, t);
        t = fmaf(lrelu02(x2 + xr.z), at.z, t);
        t = fmaf(lrelu02(x3 + xr.w), at.w, t);
        t += __shfl_xor(t, 1, 64);
        t += __shfl_xor(t, 2, 64);
        t += __shfl_xor(t, 4, 64);
        t += __shfl_xor(t, 8, 64);       // 40ch score (inactive subs add 0)
        t = (eo < deg) ? t : -1e30f;
        float p = __expf(t);
        a0 = fmaf(p, x0, a0);
        a1 = fmaf(p, x1, a1);
        a2 = fmaf(p, x2, a2);
        a3 = fmaf(p, x3, a3);
        sl += p;
    };

    for (int ch = 0; ch < deg; ch += 16) {
        int sidx = csr[min(jb + ch + sub, je - 1)];
        int s0 = __shfl(sidx, grp, 16);
        int s1 = __shfl(sidx, 4 + grp, 16);
        int s2 = __shfl(sidx, 8 + grp, 16);
        int s3 = __shfl(sidx, 12 + grp, 16);
        proc(s0, ch + grp);
        proc(s1, ch + 4 + grp);
        proc(s2, ch + 8 + grp);
        proc(s3, ch + 12 + grp);
    }
#pragma unroll
    for (int d = 16; d <= 32; d <<= 1) {
        a0 += __shfl_xor(a0, d, 64);
        a1 += __shfl_xor(a1, d, 64);
        a2 += __shfl_xor(a2, d, 64);
        a3 += __shfl_xor(a3, d, 64);
        sl += __shfl_xor(sl, d, 64);
    }
    if (grp == 0 && chact) {
        float inv = 1.f / (sl + 1e-16f);
        float4 y;
        y.x = a0 * inv + b2[cld];
        y.y = a1 * inv + b2[cld + 1];
        y.z = a2 * inv + b2[cld + 2];
        y.w = a3 * inv + b2[cld + 3];
        *(float4*)&Y[(size_t)node * 40 + cld] = y;
    }
}

// ---------------- launch ----------------
extern "C" void kernel_launch(void* const* d_in, const int* in_sizes, int n_in,
                              void* d_out, int out_size, void* d_ws, size_t ws_size,
                              hipStream_t stream) {
    const float* x = (const float*)d_in[0];
    const int* ei = (const int*)d_in[1];
    const float* Wl1 = (const float*)d_in[2];
    const float* bl1 = (const float*)d_in[3];
    const float* Wr1 = (const float*)d_in[4];
    const float* br1 = (const float*)d_in[5];
    const float* att1 = (const float*)d_in[6];
    const float* b1 = (const float*)d_in[7];
    const float* g1 = (const float*)d_in[8];
    const float* be1 = (const float*)d_in[9];
    const float* Wl2 = (const float*)d_in[10];
    const float* bl2 = (const float*)d_in[11];
    const float* Wr2 = (const float*)d_in[12];
    const float* br2 = (const float*)d_in[13];
    const float* att2 = (const float*)d_in[14];
    const float* b2 = (const float*)d_in[15];

    const int* srcs = ei;
    const int* tgts = ei + EE;

    char* ws = (char*)d_ws;
    unsigned short* XBF = (unsigned short*)(ws + OFF_XBF);
    unsigned short* XL2B = (unsigned short*)(ws + OFF_XL2B);
    float* XR2 = (float*)(ws + OFF_XR2);
    unsigned short* XL1B = (unsigned short*)(ws + OFF_XL1B);
    unsigned short* H1B = (unsigned short*)(ws + OFF_H1B);
    float* XR1 = (float*)(ws + OFF_XR1);
    unsigned char* HB = (unsigned char*)(ws + OFF_HB);
    int* BOFF = (int*)(ws + OFF_BOFF);
    float* H1pre = (float*)(ws + OFF_H1PRE);
    float* S1 = (float*)(ws + OFF_S1);
    unsigned short* BP1 = (unsigned short*)(ws + OFF_BP1);
    unsigned short* BP2 = (unsigned short*)(ws + OFF_BP2);
    float* BB1 = (float*)(ws + OFF_BB1);
    float* BB2 = (float*)(ws + OFF_BB2);
    int* DEG = (int*)(ws + OFF_DEG);
    int* OFFS = (int*)(ws + OFF_OFFS);
    int* BSUM = (int*)(ws + OFF_BSUM);
    int* CSR = (int*)(ws + OFF_CSR);

    float* Y = (float*)d_out;

    // prep: cvt x->bf16 + pack weights (no atomics)
    prep_kernel<<<(NN * 128 / 8 + 255) / 256, 256, 0, stream>>>(
        x, XBF, Wl1, bl1, Wr1, br1, Wl2, bl2, Wr2, br2, BP1, BB1, BP2, BB2);

    // CSR build: LDS counting sort (no global atomics)
    cs_hist_kernel<<<NBLK_CS, 1024, 0, stream>>>(tgts, HB);
    cs_boff_kernel<<<(NN + 255) / 256, 256, 0, stream>>>(HB, BOFF, DEG);
    scan_bsum_kernel<<<NB_SCAN, 1024, 0, stream>>>(DEG, BSUM, NN);
    scan_final_kernel<<<NB_SCAN, 1024, 0, stream>>>(DEG, BSUM, OFFS, NN);
    cs_scatter_kernel<<<NBLK_CS, 1024, 0, stream>>>(srcs, tgts, OFFS, BOFF, CSR);

    // layer-1 GEMM (bf16 MFMA): xl -> bf16 XL1B, xr -> f32 XR1
    gemm_mfma_kernel<<<(3125 + 3) / 4, 256, 0, stream>>>(XBF, BP1, BB1, XL1B, XR1, NN, 16, 128);

    // layer-1 fused per-head score+agg (L2-resident 3.2MB slice per launch)
    for (int cb = 0; cb < 4; ++cb)
        gat_head1_kernel<<<12500, 256, 0, stream>>>(XL1B, XR1, OFFS, CSR, att1, H1pre, S1, cb);

    // layer-1 softmax-divide + bias + LN + ELU -> H1 bf16
    ln1_kernel<<<12500, 256, 0, stream>>>(H1pre, S1, b1, g1, be1, H1B);

    // layer-2 GEMM (bf16 MFMA): xl -> bf16 XL2B, xr -> f32 XR2
    gemm_mfma_kernel<<<(3125 + 3) / 4, 256, 0, stream>>>(H1B, BP2, BB2, XL2B, XR2, NN, 5, 40);

    // layer-2 fused score+agg -> output
    gat_edge2_kernel<<<(NN + 3) / 4, 256, 0, stream>>>(XL2B, XR2, OFFS, CSR, att2, b2, Y);
}

// Round 15
// 227.408 us; speedup vs baseline: 1.0598x; 1.0598x over previous
//
#include <hip/hip_runtime.h>
#include <hip/hip_bf16.h>
#include <math.h>

// Problem constants
#define NN 50000
#define EE 800000
#define NB_SCAN 49    // ceil(50000/1024)
#define NBLK_CS 256   // counting-sort blocks (full-chip grid)
#define EPB (EE / NBLK_CS)  // 3125 edges per block

typedef __attribute__((ext_vector_type(8))) short bf16x8;
typedef __attribute__((ext_vector_type(4))) float f32x4;
typedef __attribute__((ext_vector_type(8))) unsigned short ushortx8;

// ---------------- workspace layout (bytes); regions phase-disjoint ----------
#define OFF_XBF   ((size_t)0)           // N*128 bf16 = 12.8M (prep..gemm1)
#define OFF_XL2B  ((size_t)0)           // N*40 bf16 = 4M (gemm2..end)
#define OFF_XR2   ((size_t)4000000)     // N*40 f32 = 8M (gemm2..end)
#define OFF_XL1B  ((size_t)12800000)    // N*128 bf16 = 12.8M (gemm1..head1)
#define OFF_H1B   ((size_t)12800000)    // N*128 bf16 (ln1..gemm2; XL1B dead)
#define OFF_XR1   ((size_t)25600000)    // N*128 f32 = 25.6M (gemm1..head1)
// [51.2M,76.8M): CSR-build scratch (HB,BOFF u8; dead before head1) then H1PRE
#define OFF_HB    ((size_t)51200000)    // 256*N u8 = 12.8M
#define OFF_BOFF  ((size_t)64000000)    // 256*N u8 = 12.8M
#define OFF_H1PRE ((size_t)51200000)    // N*128 f32 = 25.6M (head1..ln1)
#define OFF_S1    ((size_t)76800000)    // N*4 f32 = 800,000
#define OFF_BP1   ((size_t)77600000)    // 32768 bf16
#define OFF_BP2   ((size_t)77665536)    // 10240 bf16
#define OFF_BB1   ((size_t)77686016)    // 256 f32
#define OFF_BB2   ((size_t)77687040)    // 80 f32 (pad 512)
#define OFF_DEG   ((size_t)77687552)    // N int
#define OFF_OFFS  ((size_t)77887552)    // (N+1) int
#define OFF_BSUM  ((size_t)78087808)    // 64 int (pad 256)
#define OFF_CSR   ((size_t)78088064)    // E int = 3.2M (src per CSR pos)

// ---------------- helpers (proven) ----------------
__device__ __forceinline__ unsigned short f2bf(float f) {
    union { float f; unsigned u; } v;
    v.f = f;
    unsigned r = v.u + 0x7fffu + ((v.u >> 16) & 1u);
    return (unsigned short)(r >> 16);
}
__device__ __forceinline__ float bfl(unsigned u) {
    union { unsigned u; float f; } v;
    v.u = u << 16;
    return v.f;
}
__device__ __forceinline__ float bfh(unsigned u) {
    union { unsigned u; float f; } v;
    v.u = u & 0xffff0000u;
    return v.f;
}
__device__ __forceinline__ float lrelu02(float h) { return fmaxf(h, 0.2f * h); }

// ---------------- prep: cvt x->bf16 + pack weights (pure streaming) ---------
__global__ void prep_kernel(
    const float* __restrict__ x, unsigned short* __restrict__ XBF,
    const float* __restrict__ Wl1, const float* __restrict__ bl1,
    const float* __restrict__ Wr1, const float* __restrict__ br1,
    const float* __restrict__ Wl2, const float* __restrict__ bl2,
    const float* __restrict__ Wr2, const float* __restrict__ br2,
    unsigned short* __restrict__ BP1, float* __restrict__ BB1,
    unsigned short* __restrict__ BP2, float* __restrict__ BB2) {
    int i = blockIdx.x * blockDim.x + threadIdx.x;
    if (i < NN * 128 / 8) {
        const float4* p = (const float4*)x + (size_t)i * 2;
        float4 v0 = p[0], v1 = p[1];
        ushortx8 o;
        o[0] = f2bf(v0.x); o[1] = f2bf(v0.y); o[2] = f2bf(v0.z); o[3] = f2bf(v0.w);
        o[4] = f2bf(v1.x); o[5] = f2bf(v1.y); o[6] = f2bf(v1.z); o[7] = f2bf(v1.w);
        *((ushortx8*)XBF + i) = o;
    }
    if (i < 32768) {  // layer 1 B-pack: NT=16
        int j = i & 7, l = (i >> 3) & 63, nt = (i >> 9) & 15, kt = i >> 13;
        int k = kt * 32 + ((l >> 4) << 3) + j;
        int n = nt * 16 + (l & 15);
        float v = (n < 128) ? Wl1[k * 128 + n] : Wr1[k * 128 + (n - 128)];
        BP1[i] = f2bf(v);
    }
    if (i < 10240) {  // layer 2 B-pack: NT=5
        int j = i & 7, l = (i >> 3) & 63;
        int rest = i >> 9;
        int nt = rest % 5, kt = rest / 5;
        int k = kt * 32 + ((l >> 4) << 3) + j;
        int n = nt * 16 + (l & 15);
        float v = (n < 40) ? Wl2[k * 40 + n] : Wr2[k * 40 + (n - 40)];
        BP2[i] = f2bf(v);
    }
    if (i < 256) BB1[i] = (i < 128) ? bl1[i] : br1[i - 128];
    if (i < 80) BB2[i] = (i < 40) ? bl2[i] : br2[i - 40];
}

// ---------------- counting-sort CSR build (no global atomics) ---------------
// H1: per-block LDS histogram (packed u8 over all 50000 targets) -> HB[b][t]
__global__ __launch_bounds__(1024) void cs_hist_kernel(
    const int* __restrict__ tgts, unsigned char* __restrict__ HB) {
    __shared__ unsigned int cnt[NN / 4];  // 12500 u32 = 50000 packed u8
    int b = blockIdx.x;
    for (int i = threadIdx.x; i < NN / 4; i += 1024) cnt[i] = 0;
    __syncthreads();
    int e0 = b * EPB;
    for (int i = threadIdx.x; i < EPB; i += 1024) {
        int t = tgts[e0 + i];
        atomicAdd(&cnt[t >> 2], 1u << ((t & 3) * 8));
    }
    __syncthreads();
    unsigned int* out = (unsigned int*)(HB + (size_t)b * NN);
    for (int i = threadIdx.x; i < NN / 4; i += 1024) out[i] = cnt[i];
}

// H2: per-target prefix over 256 block counts -> BOFF[b][t] (u8); DEG[t]=total
__global__ void cs_boff_kernel(const unsigned char* __restrict__ HB,
                               unsigned char* __restrict__ BOFF, int* __restrict__ DEG) {
    int t = blockIdx.x * 256 + threadIdx.x;
    if (t >= NN) return;
    int run = 0;
    for (int b = 0; b < NBLK_CS; ++b) {
        BOFF[(size_t)b * NN + t] = (unsigned char)run;
        run += HB[(size_t)b * NN + t];
    }
    DEG[t] = run;
}

// H3: replay LDS histogram for local rank; pos = OFFS[t] + BOFF[b][t] + r
__global__ __launch_bounds__(1024) void cs_scatter_kernel(
    const int* __restrict__ srcs, const int* __restrict__ tgts,
    const int* __restrict__ off, const unsigned char* __restrict__ boff,
    int* __restrict__ csr) {
    __shared__ unsigned int cnt[NN / 4];
    int b = blockIdx.x;
    for (int i = threadIdx.x; i < NN / 4; i += 1024) cnt[i] = 0;
    __syncthreads();
    int e0 = b * EPB;
    const unsigned char* bo = boff + (size_t)b * NN;
    for (int i = threadIdx.x; i < EPB; i += 1024) {
        int t = tgts[e0 + i];
        int sh = (t & 3) * 8;
        unsigned old = atomicAdd(&cnt[t >> 2], 1u << sh);
        int r = (old >> sh) & 0xFF;
        csr[off[t] + (int)bo[t] + r] = srcs[e0 + i];
    }
}

// ---------------- parallel scan (proven) ----------------
__global__ __launch_bounds__(1024) void scan_bsum_kernel(
    const int* __restrict__ deg, int* __restrict__ bsum, int n) {
    __shared__ int ws[16];
    int lane = threadIdx.x & 63, w = threadIdx.x >> 6;
    int i = blockIdx.x * 1024 + threadIdx.x;
    int v = (i < n) ? deg[i] : 0;
#pragma unroll
    for (int d = 32; d >= 1; d >>= 1) v += __shfl_xor(v, d, 64);
    if (lane == 0) ws[w] = v;
    __syncthreads();
    if (threadIdx.x < 16) {
        int xv = ws[threadIdx.x];
#pragma unroll
        for (int d = 8; d >= 1; d >>= 1) xv += __shfl_xor(xv, d, 16);
        if (threadIdx.x == 0) bsum[blockIdx.x] = xv;
    }
}

__global__ __launch_bounds__(1024) void scan_final_kernel(
    const int* __restrict__ deg, const int* __restrict__ bsum,
    int* __restrict__ off, int n) {
    __shared__ int wsum[16];
    __shared__ int carrySh;
    int lane = threadIdx.x & 63, w = threadIdx.x >> 6;
    if (threadIdx.x < 64) {
        int v = ((int)threadIdx.x < (int)blockIdx.x) ? bsum[threadIdx.x] : 0;
#pragma unroll
        for (int d = 32; d >= 1; d >>= 1) v += __shfl_xor(v, d, 64);
        if (threadIdx.x == 0) carrySh = v;
    }
    int i = blockIdx.x * 1024 + threadIdx.x;
    int v = (i < n) ? deg[i] : 0;
    int incl = v;
#pragma unroll
    for (int d = 1; d < 64; d <<= 1) {
        int t = __shfl_up(incl, d, 64);
        if (lane >= d) incl += t;
    }
    if (lane == 63) wsum[w] = incl;
    __syncthreads();
    if (threadIdx.x < 16) {
        int xv = wsum[threadIdx.x];
#pragma unroll
        for (int d = 1; d < 16; d <<= 1) {
            int t = __shfl_up(xv, d, 16);
            if ((int)threadIdx.x >= d) xv += t;
        }
        wsum[threadIdx.x] = xv;
    }
    __syncthreads();
    int add = (w > 0) ? wsum[w - 1] : 0;
    int carry = carrySh;
    if (i < n) off[i + 1] = carry + incl + add;
    if (i == 0) off[0] = 0;
}

// ---------------- bf16 MFMA GEMM: split bf16/f32 outputs ---------------------
__global__ __launch_bounds__(256) void gemm_mfma_kernel(
    const unsigned short* __restrict__ Abf, const unsigned short* __restrict__ BP,
    const float* __restrict__ bias, unsigned short* __restrict__ Cbf,
    float* __restrict__ Cf, int M, int NT, int NSPLIT) {
    int wave = (blockIdx.x * blockDim.x + threadIdx.x) >> 6;
    int lane = threadIdx.x & 63;
    int r0 = wave * 16;
    if (r0 >= M) return;
    int koff = (lane >> 4) << 3;
    const unsigned short* ap = &Abf[(size_t)(r0 + (lane & 15)) * 128 + koff];
    bf16x8 a0 = *(const bf16x8*)(ap);
    bf16x8 a1 = *(const bf16x8*)(ap + 32);
    bf16x8 a2 = *(const bf16x8*)(ap + 64);
    bf16x8 a3 = *(const bf16x8*)(ap + 96);
    int NR = (NT << 4) - NSPLIT;
    int col = lane & 15;
    int rb = r0 + ((lane >> 4) << 2);
    size_t ktStride = (size_t)NT * 512;
    for (int nt = 0; nt < NT; ++nt) {
        const unsigned short* bp = &BP[((size_t)nt * 64 + lane) * 8];
        f32x4 acc = {0.f, 0.f, 0.f, 0.f};
        acc = __builtin_amdgcn_mfma_f32_16x16x32_bf16(a0, *(const bf16x8*)(bp), acc, 0, 0, 0);
        acc = __builtin_amdgcn_mfma_f32_16x16x32_bf16(a1, *(const bf16x8*)(bp + ktStride), acc, 0, 0, 0);
        acc = __builtin_amdgcn_mfma_f32_16x16x32_bf16(a2, *(const bf16x8*)(bp + 2 * ktStride), acc, 0, 0, 0);
        acc = __builtin_amdgcn_mfma_f32_16x16x32_bf16(a3, *(const bf16x8*)(bp + 3 * ktStride), acc, 0, 0, 0);
        int c = (nt << 4) + col;
        float bb = bias[c];
        if (c < NSPLIT) {
#pragma unroll
            for (int j = 0; j < 4; ++j) Cbf[(size_t)(rb + j) * NSPLIT + c] = f2bf(acc[j] + bb);
        } else {
#pragma unroll
            for (int j = 0; j < 4; ++j) Cf[(size_t)(rb + j) * NR + (c - NSPLIT)] = acc[j] + bb;
        }
    }
}

// ---------------- layer-1 per-head fused score+agg kernel --------------------
__global__ __launch_bounds__(256) void gat_head1_kernel(
    const unsigned short* __restrict__ XL1B, const float* __restrict__ XR1,
    const int* __restrict__ off, const int* __restrict__ csr,
    const float* __restrict__ att, float* __restrict__ H1pre,
    float* __restrict__ S1, int cb) {
    int wid = threadIdx.x >> 6;
    int lane = threadIdx.x & 63;
    int node = blockIdx.x * 4 + wid;
    if (node >= NN) return;
    int grp = lane >> 4;
    int sub = lane & 15;
    int coff = cb * 32 + sub * 2;
    float2 xr = *(const float2*)&XR1[(size_t)node * 128 + coff];
    float2 at = *(const float2*)&att[coff];
    const unsigned short* base = XL1B + coff;
    float a0 = 0.f, a1 = 0.f, sl = 0.f;
    int jb = off[node], je = off[node + 1];
    int deg = je - jb;

    auto proc = [&](int srcv, int eo) {
        unsigned u = *(const unsigned*)(base + (size_t)srcv * 128);
        float x0 = bfl(u), x1 = bfh(u);
        float t = lrelu02(x0 + xr.x) * at.x;
        t = fmaf(lrelu02(x1 + xr.y), at.y, t);
        t += __shfl_xor(t, 1, 64);
        t += __shfl_xor(t, 2, 64);
        t += __shfl_xor(t, 4, 64);
        t += __shfl_xor(t, 8, 64);       // head score over 16 subs
        t = (eo < deg) ? t : -1e30f;
        float p = __expf(t);
        a0 = fmaf(p, x0, a0);
        a1 = fmaf(p, x1, a1);
        sl += p;
    };

    for (int ch = 0; ch < deg; ch += 16) {
        int sidx = csr[min(jb + ch + sub, je - 1)];
        int s0 = __shfl(sidx, grp, 16);
        int s1 = __shfl(sidx, 4 + grp, 16);
        int s2 = __shfl(sidx, 8 + grp, 16);
        int s3 = __shfl(sidx, 12 + grp, 16);
        proc(s0, ch + grp);
        proc(s1, ch + 4 + grp);
        proc(s2, ch + 8 + grp);
        proc(s3, ch + 12 + grp);
    }
#pragma unroll
    for (int d = 16; d <= 32; d <<= 1) {
        a0 += __shfl_xor(a0, d, 64);
        a1 += __shfl_xor(a1, d, 64);
        sl += __shfl_xor(sl, d, 64);
    }
    if (grp == 0) {
        float2 v;
        v.x = a0;
        v.y = a1;
        *(float2*)&H1pre[(size_t)node * 128 + coff] = v;
        if (sub == 0) S1[node * 4 + cb] = sl;
    }
}

// ---------------- layer-1 divide + bias + LN + ELU -> H1 bf16 ---------------
__global__ __launch_bounds__(256) void ln1_kernel(
    const float* __restrict__ H1pre, const float* __restrict__ S1,
    const float* __restrict__ b1, const float* __restrict__ g1,
    const float* __restrict__ be1, unsigned short* __restrict__ H1B) {
    int wid = threadIdx.x >> 6;
    int lane = threadIdx.x & 63;
    int node = blockIdx.x * 4 + wid;
    if (node >= NN) return;
    int c = lane * 2;
    float2 v = *(const float2*)&H1pre[(size_t)node * 128 + c];
    float sl = S1[node * 4 + (lane >> 4)];
    float inv = 1.f / (sl + 1e-16f);
    float o0 = v.x * inv + b1[c];
    float o1 = v.y * inv + b1[c + 1];
    float sum = o0 + o1, sq = o0 * o0 + o1 * o1;
#pragma unroll
    for (int d = 32; d >= 1; d >>= 1) {
        sum += __shfl_xor(sum, d, 64);
        sq += __shfl_xor(sq, d, 64);
    }
    float mu = sum * (1.f / 128.f);
    float var = sq * (1.f / 128.f) - mu * mu;
    float rs = rsqrtf(var + 1e-5f);
    float y0 = (o0 - mu) * rs * g1[c] + be1[c];
    float y1 = (o1 - mu) * rs * g1[c + 1] + be1[c + 1];
    y0 = y0 > 0.f ? y0 : expm1f(y0);
    y1 = y1 > 0.f ? y1 : expm1f(y1);
    unsigned o = (unsigned)f2bf(y0) | ((unsigned)f2bf(y1) << 16);
    ((unsigned*)H1B)[(size_t)node * 64 + lane] = o;
}

// ---------------- layer-2 fused score+agg (single head, 40ch) ---------------
__global__ __launch_bounds__(256) void gat_edge2_kernel(
    const unsigned short* __restrict__ XL2B, const float* __restrict__ XR2,
    const int* __restrict__ off, const int* __restrict__ csr,
    const float* __restrict__ att2, const float* __restrict__ b2,
    float* __restrict__ Y) {
    int wid = threadIdx.x >> 6;
    int lane = threadIdx.x & 63;
    int node = blockIdx.x * 4 + wid;
    if (node >= NN) return;
    int grp = lane >> 4;
    int sub = lane & 15;
    bool chact = sub < 10;
    int cld = chact ? sub * 4 : 0;
    float4 xr = make_float4(0.f, 0.f, 0.f, 0.f);
    float4 at = make_float4(0.f, 0.f, 0.f, 0.f);
    if (chact) {
        xr = *(const float4*)&XR2[(size_t)node * 40 + cld];
        at = *(const float4*)&att2[cld];
    }
    float a0 = 0.f, a1 = 0.f, a2 = 0.f, a3 = 0.f, sl = 0.f;
    int jb = off[node], je = off[node + 1];
    int deg = je - jb;

    auto proc = [&](int srcv, int eo) {
        uint2 u = *(const uint2*)(XL2B + (size_t)srcv * 40 + cld);
        float x0 = bfl(u.x), x1 = bfh(u.x), x2 = bfl(u.y), x3 = bfh(u.y);
        float t = lrelu02(x0 + xr.x) * at.x;
        t = fmaf(lrelu02(x1 + xr.y), at.y, t);
        t = fmaf(lrelu02(x2 + xr.z), at.z, t);
        t = fmaf(lrelu02(x3 + xr.w), at.w, t);
        t += __shfl_xor(t, 1, 64);
        t += __shfl_xor(t, 2, 64);
        t += __shfl_xor(t, 4, 64);
        t += __shfl_xor(t, 8, 64);       // 40ch score (inactive subs add 0)
        t = (eo < deg) ? t : -1e30f;
        float p = __expf(t);
        a0 = fmaf(p, x0, a0);
        a1 = fmaf(p, x1, a1);
        a2 = fmaf(p, x2, a2);
        a3 = fmaf(p, x3, a3);
        sl += p;
    };

    for (int ch = 0; ch < deg; ch += 16) {
        int sidx = csr[min(jb + ch + sub, je - 1)];
        int s0 = __shfl(sidx, grp, 16);
        int s1 = __shfl(sidx, 4 + grp, 16);
        int s2 = __shfl(sidx, 8 + grp, 16);
        int s3 = __shfl(sidx, 12 + grp, 16);
        proc(s0, ch + grp);
        proc(s1, ch + 4 + grp);
        proc(s2, ch + 8 + grp);
        proc(s3, ch + 12 + grp);
    }
#pragma unroll
    for (int d = 16; d <= 32; d <<= 1) {
        a0 += __shfl_xor(a0, d, 64);
        a1 += __shfl_xor(a1, d, 64);
        a2 += __shfl_xor(a2, d, 64);
        a3 += __shfl_xor(a3, d, 64);
        sl += __shfl_xor(sl, d, 64);
    }
    if (grp == 0 && chact) {
        float inv = 1.f / (sl + 1e-16f);
        float4 y;
        y.x = a0 * inv + b2[cld];
        y.y = a1 * inv + b2[cld + 1];
        y.z = a2 * inv + b2[cld + 2];
        y.w = a3 * inv + b2[cld + 3];
        *(float4*)&Y[(size_t)node * 40 + cld] = y;
    }
}

// ---------------- launch ----------------
extern "C" void kernel_launch(void* const* d_in, const int* in_sizes, int n_in,
                              void* d_out, int out_size, void* d_ws, size_t ws_size,
                              hipStream_t stream) {
    const float* x = (const float*)d_in[0];
    const int* ei = (const int*)d_in[1];
    const float* Wl1 = (const float*)d_in[2];
    const float* bl1 = (const float*)d_in[3];
    const float* Wr1 = (const float*)d_in[4];
    const float* br1 = (const float*)d_in[5];
    const float* att1 = (const float*)d_in[6];
    const float* b1 = (const float*)d_in[7];
    const float* g1 = (const float*)d_in[8];
    const float* be1 = (const float*)d_in[9];
    const float* Wl2 = (const float*)d_in[10];
    const float* bl2 = (const float*)d_in[11];
    const float* Wr2 = (const float*)d_in[12];
    const float* br2 = (const float*)d_in[13];
    const float* att2 = (const float*)d_in[14];
    const float* b2 = (const float*)d_in[15];

    const int* srcs = ei;
    const int* tgts = ei + EE;

    char* ws = (char*)d_ws;
    unsigned short* XBF = (unsigned short*)(ws + OFF_XBF);
    unsigned short* XL2B = (unsigned short*)(ws + OFF_XL2B);
    float* XR2 = (float*)(ws + OFF_XR2);
    unsigned short* XL1B = (unsigned short*)(ws + OFF_XL1B);
    unsigned short* H1B = (unsigned short*)(ws + OFF_H1B);
    float* XR1 = (float*)(ws + OFF_XR1);
    unsigned char* HB = (unsigned char*)(ws + OFF_HB);
    unsigned char* BOFF = (unsigned char*)(ws + OFF_BOFF);
    float* H1pre = (float*)(ws + OFF_H1PRE);
    float* S1 = (float*)(ws + OFF_S1);
    unsigned short* BP1 = (unsigned short*)(ws + OFF_BP1);
    unsigned short* BP2 = (unsigned short*)(ws + OFF_BP2);
    float* BB1 = (float*)(ws + OFF_BB1);
    float* BB2 = (float*)(ws + OFF_BB2);
    int* DEG = (int*)(ws + OFF_DEG);
    int* OFFS = (int*)(ws + OFF_OFFS);
    int* BSUM = (int*)(ws + OFF_BSUM);
    int* CSR = (int*)(ws + OFF_CSR);

    float* Y = (float*)d_out;

    // prep: cvt x->bf16 + pack weights (no atomics)
    prep_kernel<<<(NN * 128 / 8 + 255) / 256, 256, 0, stream>>>(
        x, XBF, Wl1, bl1, Wr1, br1, Wl2, bl2, Wr2, br2, BP1, BB1, BP2, BB2);

    // CSR build: LDS counting sort, full-chip grid (no global atomics)
    cs_hist_kernel<<<NBLK_CS, 1024, 0, stream>>>(tgts, HB);
    cs_boff_kernel<<<(NN + 255) / 256, 256, 0, stream>>>(HB, BOFF, DEG);
    scan_bsum_kernel<<<NB_SCAN, 1024, 0, stream>>>(DEG, BSUM, NN);
    scan_final_kernel<<<NB_SCAN, 1024, 0, stream>>>(DEG, BSUM, OFFS, NN);
    cs_scatter_kernel<<<NBLK_CS, 1024, 0, stream>>>(srcs, tgts, OFFS, BOFF, CSR);

    // layer-1 GEMM (bf16 MFMA): xl -> bf16 XL1B, xr -> f32 XR1
    gemm_mfma_kernel<<<(3125 + 3) / 4, 256, 0, stream>>>(XBF, BP1, BB1, XL1B, XR1, NN, 16, 128);

    // layer-1 fused per-head score+agg (L2-resident 3.2MB slice per launch)
    for (int cb = 0; cb < 4; ++cb)
        gat_head1_kernel<<<12500, 256, 0, stream>>>(XL1B, XR1, OFFS, CSR, att1, H1pre, S1, cb);

    // layer-1 softmax-divide + bias + LN + ELU -> H1 bf16
    ln1_kernel<<<12500, 256, 0, stream>>>(H1pre, S1, b1, g1, be1, H1B);

    // layer-2 GEMM (bf16 MFMA): xl -> bf16 XL2B, xr -> f32 XR2
    gemm_mfma_kernel<<<(3125 + 3) / 4, 256, 0, stream>>>(H1B, BP2, BB2, XL2B, XR2, NN, 5, 40);

    // layer-2 fused score+agg -> output
    gat_edge2_kernel<<<(NN + 3) / 4, 256, 0, stream>>>(XL2B, XR2, OFFS, CSR, att2, b2, Y);
}